// Round 2
// baseline (190.802 us; speedup 1.0000x reference)
//
#include <hip/hip_runtime.h>

// Problem constants (from reference)
#define BB 16
#define TT 4096
#define HH 64
#define DD 10
#define MM 640   // HH*DD

// ---------------------------------------------------------------------------
// Kernel 0: zero the ksum workspace (B*M floats = 40 KB)
// ---------------------------------------------------------------------------
__global__ void zero_ws_kernel(float* __restrict__ ws, int n) {
    int i = blockIdx.x * blockDim.x + threadIdx.x;
    if (i < n) ws[i] = 0.0f;
}

// ---------------------------------------------------------------------------
// Kernel 1: ksum[b][m] = sum_t key[b][t][m]
// Grid: x = 10 (2560 float4-columns / 256), y = 64 t-chunks of 64 rows.
// Coalesced float4 reads; 4 atomicAdds per thread (64 contenders/address).
// ---------------------------------------------------------------------------
__global__ void ksum_kernel(const float* __restrict__ key, float* __restrict__ ksum) {
    int g = blockIdx.x * blockDim.x + threadIdx.x;   // 0..2559 = b*160 + c
    int b = g / 160;
    int c = g % 160;                                  // float4 column index
    int t0 = blockIdx.y * 64;

    const float4* p = reinterpret_cast<const float4*>(key)
                    + (size_t)b * TT * 160 + (size_t)t0 * 160 + c;
    float4 acc = make_float4(0.f, 0.f, 0.f, 0.f);
    #pragma unroll 8
    for (int i = 0; i < 64; ++i) {
        float4 x = p[(size_t)i * 160];
        acc.x += x.x; acc.y += x.y; acc.z += x.z; acc.w += x.w;
    }
    float* dst = ksum + b * MM + c * 4;
    atomicAdd(dst + 0, acc.x);
    atomicAdd(dst + 1, acc.y);
    atomicAdd(dst + 2, acc.z);
    atomicAdd(dst + 3, acc.w);
}

// ---------------------------------------------------------------------------
// Robust tanh: never overflows (uses exp of a NEGATIVE argument only).
// tanh(x) = sign(x) * (1 - e^{-2|x|}) / (1 + e^{-2|x|})
// ---------------------------------------------------------------------------
__device__ __forceinline__ float tanh_fast(float x) {
    float ax = fabsf(x);
    float e2 = __expf(-2.0f * ax);        // in (0,1], no overflow ever
    float th = (1.0f - e2) / (1.0f + e2); // tanh(|x|) in [0,1)
    return copysignf(th, x);
}

// ---------------------------------------------------------------------------
// Kernel 2: out[b,h,t] = sum_d softmax_d(tanh(q*ksum/sqrt(10))) * v
// One thread per (b, head-group of 16, t). Lanes vary over t:
//   - writes out[b,h,t] coalesced (stride-1 in t per h)
//   - q/v reads: each lane streams its own contiguous 640B chunk (L1 reuse)
//   - ksum reads wave-uniform -> L1 hits
// ---------------------------------------------------------------------------
__global__ void attn_kernel(const float* __restrict__ q,
                            const float* __restrict__ v,
                            const float* __restrict__ ksum,
                            float* __restrict__ out) {
    int g = blockIdx.x * blockDim.x + threadIdx.x;   // ((b*4 + hg)*T + t)
    int t  = g & (TT - 1);
    int hg = (g >> 12) & 3;           // head group (16 heads each)
    int b  = g >> 14;

    const float* qp = q    + (size_t)(b * TT + t) * MM + hg * 160;
    const float* vp = v    + (size_t)(b * TT + t) * MM + hg * 160;
    const float* ks = ksum + b * MM + hg * 160;
    float*       op = out  + ((size_t)b * HH + hg * 16) * TT + t;

    const float R = 0.316227766016838f;   // 1/sqrt(10)

    for (int h = 0; h < 16; ++h) {
        float sum = 0.f, dot = 0.f;
        #pragma unroll
        for (int d2 = 0; d2 < 5; ++d2) {
            float2 qq = *reinterpret_cast<const float2*>(qp + h * 10 + d2 * 2);
            float2 vv = *reinterpret_cast<const float2*>(vp + h * 10 + d2 * 2);
            float2 kk = *reinterpret_cast<const float2*>(ks + h * 10 + d2 * 2);
            {
                float e = __expf(tanh_fast(qq.x * kk.x * R));
                sum += e; dot += e * vv.x;
            }
            {
                float e = __expf(tanh_fast(qq.y * kk.y * R));
                sum += e; dot += e * vv.y;
            }
        }
        op[(size_t)h * TT] = dot / sum;
    }
}

// ---------------------------------------------------------------------------
extern "C" void kernel_launch(void* const* d_in, const int* in_sizes, int n_in,
                              void* d_out, int out_size, void* d_ws, size_t ws_size,
                              hipStream_t stream) {
    const float* q = (const float*)d_in[0];
    const float* k = (const float*)d_in[1];
    const float* v = (const float*)d_in[2];
    // d_in[3] = W, d_in[4] = b : dead code (softmax over size-1 axis == 1)
    float* out  = (float*)d_out;
    float* ksum = (float*)d_ws;    // B*M floats = 40 KB

    zero_ws_kernel<<<dim3((BB * MM + 255) / 256), dim3(256), 0, stream>>>(ksum, BB * MM);
    ksum_kernel<<<dim3(10, 64), dim3(256), 0, stream>>>(k, ksum);
    attn_kernel<<<dim3((BB * 4 * TT) / 256), dim3(256), 0, stream>>>(q, v, ksum, out);
}

// Round 3
// 116.629 us; speedup vs baseline: 1.6360x; 1.6360x over previous
//
#include <hip/hip_runtime.h>

// Problem constants (from reference)
#define BB 16
#define TT 4096
#define HH 64
#define DD 10
#define MM 640   // HH*DD

#define TROWS 16          // t-rows per block in attn kernel
#define PADF  161         // padded row stride in floats (breaks 32-way bank pattern)

// ---------------------------------------------------------------------------
// Kernel 0: zero the ksum workspace (B*M floats = 40 KB)
// ---------------------------------------------------------------------------
__global__ void zero_ws_kernel(float* __restrict__ ws, int n) {
    int i = blockIdx.x * blockDim.x + threadIdx.x;
    if (i < n) ws[i] = 0.0f;
}

// ---------------------------------------------------------------------------
// Kernel 1: ksum[b][m] = sum_t key[b][t][m]
// Coalesced float4 reads; atomicAdd partials (64 contenders/address).
// ---------------------------------------------------------------------------
__global__ void ksum_kernel(const float* __restrict__ key, float* __restrict__ ksum) {
    int g = blockIdx.x * blockDim.x + threadIdx.x;   // 0..2559 = b*160 + c
    int b = g / 160;
    int c = g % 160;                                  // float4 column index
    int t0 = blockIdx.y * 64;

    const float4* p = reinterpret_cast<const float4*>(key)
                    + (size_t)b * TT * 160 + (size_t)t0 * 160 + c;
    float4 acc = make_float4(0.f, 0.f, 0.f, 0.f);
    #pragma unroll 8
    for (int i = 0; i < 64; ++i) {
        float4 x = p[(size_t)i * 160];
        acc.x += x.x; acc.y += x.y; acc.z += x.z; acc.w += x.w;
    }
    float* dst = ksum + b * MM + c * 4;
    atomicAdd(dst + 0, acc.x);
    atomicAdd(dst + 1, acc.y);
    atomicAdd(dst + 2, acc.z);
    atomicAdd(dst + 3, acc.w);
}

// ---------------------------------------------------------------------------
// Robust tanh: never overflows (exp of a negative argument only).
// ---------------------------------------------------------------------------
__device__ __forceinline__ float tanh_fast(float x) {
    float ax = fabsf(x);
    float e2 = __expf(-2.0f * ax);        // in (0,1]
    float th = (1.0f - e2) / (1.0f + e2);
    return copysignf(th, x);
}

// ---------------------------------------------------------------------------
// Kernel 2 (LDS-staged): out[b,h,t] = sum_d softmax_d(tanh(q*ksum/sqrt(10)))*v
// Block = 256 threads, owns (b, hg, 16 t-rows).
//   stage:   q/v tiles [16][160] -> LDS (coalesced float4 global reads)
//   compute: thread (row = tid&15, head = tid>>4) reads LDS (<=3-way bank)
//   write:   out[b, hg*16+head, t0+row] -- 64B segments per quarter-wave
// ---------------------------------------------------------------------------
__global__ void __launch_bounds__(256)
attn_kernel(const float* __restrict__ q,
            const float* __restrict__ v,
            const float* __restrict__ ksum,
            float* __restrict__ out) {
    __shared__ float qs[TROWS * PADF];
    __shared__ float vs[TROWS * PADF];

    const int tid = threadIdx.x;
    const int t0  = blockIdx.x * TROWS;
    const int hg  = blockIdx.y;          // head group (16 heads)
    const int b   = blockIdx.z;

    // ---- stage: 640 float4 per tensor, coalesced ----
    const float4* qg = reinterpret_cast<const float4*>(q)
                     + ((size_t)(b * TT + t0)) * 160 + hg * 40;
    const float4* vg = reinterpret_cast<const float4*>(v)
                     + ((size_t)(b * TT + t0)) * 160 + hg * 40;

    #pragma unroll
    for (int i = 0; i < 3; ++i) {
        int idx = tid + 256 * i;                 // 0..639
        if (idx < TROWS * 40) {
            int row = idx / 40;
            int c   = idx % 40;
            float4 xq = qg[(size_t)row * 160 + c];
            float4 xv = vg[(size_t)row * 160 + c];
            int base = row * PADF + c * 4;
            qs[base + 0] = xq.x; qs[base + 1] = xq.y;
            qs[base + 2] = xq.z; qs[base + 3] = xq.w;
            vs[base + 0] = xv.x; vs[base + 1] = xv.y;
            vs[base + 2] = xv.z; vs[base + 3] = xv.w;
        }
    }
    __syncthreads();

    // ---- compute: one (row, head) pair per thread ----
    const int row  = tid & (TROWS - 1);
    const int head = tid >> 4;                   // 0..15
    const float* ks = ksum + b * MM + hg * 160 + head * 10;
    const float R = 0.316227766016838f;          // 1/sqrt(10)

    const int lbase = row * PADF + head * 10;
    float sum = 0.f, dot = 0.f;
    #pragma unroll
    for (int d = 0; d < 10; ++d) {
        float e = __expf(tanh_fast(qs[lbase + d] * ks[d] * R));
        sum += e;
        dot += e * vs[lbase + d];
    }
    out[((size_t)(b * HH + hg * 16 + head)) * TT + t0 + row] = dot / sum;
}

// ---------------------------------------------------------------------------
extern "C" void kernel_launch(void* const* d_in, const int* in_sizes, int n_in,
                              void* d_out, int out_size, void* d_ws, size_t ws_size,
                              hipStream_t stream) {
    const float* q = (const float*)d_in[0];
    const float* k = (const float*)d_in[1];
    const float* v = (const float*)d_in[2];
    // d_in[3] = W, d_in[4] = b : dead code (softmax over size-1 axis == 1)
    float* out  = (float*)d_out;
    float* ksum = (float*)d_ws;    // B*M floats = 40 KB

    zero_ws_kernel<<<dim3((BB * MM + 255) / 256), dim3(256), 0, stream>>>(ksum, BB * MM);
    ksum_kernel<<<dim3(10, 64), dim3(256), 0, stream>>>(k, ksum);
    attn_kernel<<<dim3(TT / TROWS, 4, BB), dim3(256), 0, stream>>>(q, v, ksum, out);
}

// Round 4
// 115.835 us; speedup vs baseline: 1.6472x; 1.0068x over previous
//
#include <hip/hip_runtime.h>

// Problem constants (from reference)
#define BB 16
#define TT 4096
#define HH 64
#define DD 10
#define MM 640   // HH*DD

#define TROWS 16          // t-rows per attn block
#define PADF  161         // padded LDS row stride (odd -> banks spread, <=2-way)

// ---------------------------------------------------------------------------
// Kernel 0: zero the ksum workspace (B*M floats = 40 KB)
// ---------------------------------------------------------------------------
__global__ void zero_ws_kernel(float* __restrict__ ws, int n) {
    int i = blockIdx.x * blockDim.x + threadIdx.x;
    if (i < n) ws[i] = 0.0f;
}

// ---------------------------------------------------------------------------
// Kernel 1: ksum[b][m] = sum_t key[b][t][m]
// 32-row chunks, grid (10,128) = 1280 blocks (-> 5 blocks/CU), fully
// unrolled 32 independent float4 loads per thread (high MLP), 4 accumulators.
// ---------------------------------------------------------------------------
__global__ void __launch_bounds__(256)
ksum_kernel(const float* __restrict__ key, float* __restrict__ ksum) {
    int g = blockIdx.x * blockDim.x + threadIdx.x;   // 0..2559 = b*160 + c
    int b = g / 160;
    int c = g % 160;                                  // float4 column index
    int t0 = blockIdx.y * 32;

    const float4* p = reinterpret_cast<const float4*>(key)
                    + (size_t)b * TT * 160 + (size_t)t0 * 160 + c;

    float4 a0 = make_float4(0.f,0.f,0.f,0.f);
    float4 a1 = make_float4(0.f,0.f,0.f,0.f);
    float4 a2 = make_float4(0.f,0.f,0.f,0.f);
    float4 a3 = make_float4(0.f,0.f,0.f,0.f);
    #pragma unroll
    for (int i = 0; i < 32; i += 4) {
        float4 x0 = p[(size_t)(i + 0) * 160];
        float4 x1 = p[(size_t)(i + 1) * 160];
        float4 x2 = p[(size_t)(i + 2) * 160];
        float4 x3 = p[(size_t)(i + 3) * 160];
        a0.x += x0.x; a0.y += x0.y; a0.z += x0.z; a0.w += x0.w;
        a1.x += x1.x; a1.y += x1.y; a1.z += x1.z; a1.w += x1.w;
        a2.x += x2.x; a2.y += x2.y; a2.z += x2.z; a2.w += x2.w;
        a3.x += x3.x; a3.y += x3.y; a3.z += x3.z; a3.w += x3.w;
    }
    float sx = (a0.x + a1.x) + (a2.x + a3.x);
    float sy = (a0.y + a1.y) + (a2.y + a3.y);
    float sz = (a0.z + a1.z) + (a2.z + a3.z);
    float sw = (a0.w + a1.w) + (a2.w + a3.w);

    float* dst = ksum + b * MM + c * 4;
    atomicAdd(dst + 0, sx);
    atomicAdd(dst + 1, sy);
    atomicAdd(dst + 2, sz);
    atomicAdd(dst + 3, sw);
}

// ---------------------------------------------------------------------------
// Robust tanh: never overflows (exp of a negative argument only).
// ---------------------------------------------------------------------------
__device__ __forceinline__ float tanh_fast(float x) {
    float ax = fabsf(x);
    float e2 = __expf(-2.0f * ax);        // in (0,1]
    float th = (1.0f - e2) / (1.0f + e2);
    return copysignf(th, x);
}

// ---------------------------------------------------------------------------
// Kernel 2 (reg-staged LDS): out[b,h,t] = sum_d softmax_d(tanh(q*ks/sqrt(10)))*v
// BLOCK=128, TROWS=16: each thread issues exactly 5 float4 loads per tensor
// (all 10 in flight before LDS writes -> high MLP), then computes 2
// (row,head) outputs from LDS.
// ---------------------------------------------------------------------------
__global__ void __launch_bounds__(128)
attn_kernel(const float* __restrict__ q,
            const float* __restrict__ v,
            const float* __restrict__ ksum,
            float* __restrict__ out) {
    __shared__ float qs[TROWS * PADF];
    __shared__ float vs[TROWS * PADF];

    const int tid = threadIdx.x;          // 0..127
    const int t0  = blockIdx.x * TROWS;
    const int hg  = blockIdx.y;           // head group (16 heads)
    const int b   = blockIdx.z;

    const float4* qg = reinterpret_cast<const float4*>(q)
                     + ((size_t)(b * TT + t0)) * 160 + hg * 40;
    const float4* vg = reinterpret_cast<const float4*>(v)
                     + ((size_t)(b * TT + t0)) * 160 + hg * 40;

    // ---- stage: load 5+5 float4 into registers (back-to-back), then LDS ----
    float4 rq[5], rv[5];
    #pragma unroll
    for (int i = 0; i < 5; ++i) {
        int idx = tid + 128 * i;          // 0..639
        int row = idx / 40;
        int c   = idx % 40;
        rq[i] = qg[(size_t)row * 160 + c];
        rv[i] = vg[(size_t)row * 160 + c];
    }
    #pragma unroll
    for (int i = 0; i < 5; ++i) {
        int idx  = tid + 128 * i;
        int row  = idx / 40;
        int c    = idx % 40;
        int base = row * PADF + c * 4;
        qs[base + 0] = rq[i].x; qs[base + 1] = rq[i].y;
        qs[base + 2] = rq[i].z; qs[base + 3] = rq[i].w;
        vs[base + 0] = rv[i].x; vs[base + 1] = rv[i].y;
        vs[base + 2] = rv[i].z; vs[base + 3] = rv[i].w;
    }
    __syncthreads();

    // ---- compute: 2 (row, head) outputs per thread ----
    const float R = 0.316227766016838f;   // 1/sqrt(10)
    #pragma unroll
    for (int o = 0; o < 2; ++o) {
        int p    = tid + o * 128;         // 0..255
        int row  = p & (TROWS - 1);
        int head = p >> 4;                // 0..15
        const float* ks = ksum + b * MM + hg * 160 + head * 10;

        int lbase = row * PADF + head * 10;
        float sum = 0.f, dot = 0.f;
        #pragma unroll
        for (int d = 0; d < 10; ++d) {
            float e = __expf(tanh_fast(qs[lbase + d] * ks[d] * R));
            sum += e;
            dot += e * vs[lbase + d];
        }
        out[((size_t)(b * HH + hg * 16 + head)) * TT + t0 + row] = dot / sum;
    }
}

// ---------------------------------------------------------------------------
extern "C" void kernel_launch(void* const* d_in, const int* in_sizes, int n_in,
                              void* d_out, int out_size, void* d_ws, size_t ws_size,
                              hipStream_t stream) {
    const float* q = (const float*)d_in[0];
    const float* k = (const float*)d_in[1];
    const float* v = (const float*)d_in[2];
    // d_in[3] = W, d_in[4] = b : dead code (softmax over size-1 axis == 1)
    float* out  = (float*)d_out;
    float* ksum = (float*)d_ws;    // B*M floats = 40 KB

    zero_ws_kernel<<<dim3((BB * MM + 255) / 256), dim3(256), 0, stream>>>(ksum, BB * MM);
    ksum_kernel<<<dim3(10, 128), dim3(256), 0, stream>>>(k, ksum);
    attn_kernel<<<dim3(TT / TROWS, 4, BB), dim3(128), 0, stream>>>(q, v, ksum, out);
}